// Round 13
// baseline (66.656 us; speedup 1.0000x reference)
//
#include <hip/hip_runtime.h>
#include <math.h>

#define N_NODES 32
#define DIM     128
#define NTHR_P  256
#define PREP_BLOCKS 128   // 0..63 hist; 64..127 packing
#define NTHR_G  512       // 8 waves, 2 waves/SIMD -> 256 VGPR budget
#define GNN_BLOCKS 256    // ALL blocks compute redundantly; block 0 writes out

#define SHS 132   // fp32 row stride (elements)
#define SBS 136   // bf16 row stride (elements; 272 B)
#define STS 40    // bf16 transposed stride (80 B)

typedef __attribute__((ext_vector_type(8))) short bf16x8;
typedef __attribute__((ext_vector_type(4))) float f32x4;

// round-to-nearest-even f32 -> bf16 bits (finite values only)
__device__ __forceinline__ unsigned short f2bf(float f) {
  unsigned int u = __float_as_uint(f);
  u += 0x7fffu + ((u >> 16) & 1u);
  return (unsigned short)(u >> 16);
}
__device__ __forceinline__ float bf2f(unsigned short b) {
  return __uint_as_float(((unsigned int)b) << 16);
}

#define LOG2E 1.44269504088896340736f
__device__ __forceinline__ float fexp2(float x) { return __builtin_amdgcn_exp2f(x); }
__device__ __forceinline__ float frcp(float x)  { return __builtin_amdgcn_rcpf(x); }
__device__ __forceinline__ float sigm(float x)  { return frcp(1.f + fexp2(-LOG2E * x)); }
__device__ __forceinline__ float ftanh(float x) { return 1.f - 2.f * frcp(1.f + fexp2((2.f * LOG2E) * x)); }

// ---------------- prep: hist (blocks 0..63) + packing (blocks 64..127) ------
struct PrepParams {
  const int* es; const int* ed; const int* ef; int E;
  const float* w_ih; const float* w_hh; const float* fc1_w;
  const int* nt; const int* tr; const float* ne_w; const float* te_w;
  int* hA; int* hF;
  unsigned short* blobBw;   // 12288 x 16B  B-fragments
  unsigned short* blobFc1;  // 128x256 bf16 linear
  float* blobH0;            // 32x128 fp32 h0
  unsigned short* blobHT;   // 128x32 bf16 h0^T
};

__global__ __launch_bounds__(NTHR_P) void prep_kernel(PrepParams p)
{
  const int b = blockIdx.x;
  const int t = threadIdx.x;

  if (b < 64) {   // ---------------- histogram ------------------------------
    __shared__ int lA[N_NODES * N_NODES];
    __shared__ int lF[N_NODES * 6];
    for (int i = t; i < N_NODES * N_NODES; i += NTHR_P) lA[i] = 0;
    for (int i = t; i < N_NODES * 6;       i += NTHR_P) lF[i] = 0;
    __syncthreads();

    const int E4 = p.E >> 2;
    const int4* es4 = (const int4*)p.es;
    const int4* ed4 = (const int4*)p.ed;
    const int4* ef4 = (const int4*)p.ef;
    #define DO_EDGE(S, D, F) \
      if ((unsigned)(S) < N_NODES && (unsigned)(D) < N_NODES) { \
        atomicAdd(&lA[(D) * N_NODES + (S)], 1); \
        atomicAdd(&lF[(D) * 6 + (F)], 1); }
    for (int i = b * NTHR_P + t; i < E4; i += 64 * NTHR_P) {
      int4 s4 = es4[i], d4 = ed4[i], f4 = ef4[i];
      DO_EDGE(s4.x, d4.x, f4.x)
      DO_EDGE(s4.y, d4.y, f4.y)
      DO_EDGE(s4.z, d4.z, f4.z)
      DO_EDGE(s4.w, d4.w, f4.w)
    }
    if (b == 0) {
      for (int e = (E4 << 2) + t; e < p.E; e += NTHR_P) {
        int s = p.es[e], d = p.ed[e], f = p.ef[e];
        DO_EDGE(s, d, f)
      }
    }
    #undef DO_EDGE
    __syncthreads();
    for (int i = t; i < N_NODES * N_NODES; i += NTHR_P) { int v = lA[i]; if (v) atomicAdd(&p.hA[i], v); }
    for (int i = t; i < N_NODES * 6;       i += NTHR_P) { int v = lF[i]; if (v) atomicAdd(&p.hF[i], v); }
    return;
  }

  // ---------------- packing (blocks 64..127) --------------------------------
  const int gid = (b - 64) * NTHR_P + t;   // 0..16383
  if (gid < 12288) {
    // B-frag (mfma_16x16x32_bf16): tile id = ((q*8+nb)*4+kt), lane l.
    const int l  = gid & 63;
    const int kt = (gid >> 6) & 3;
    const int nb = (gid >> 8) & 7;
    const int q  = gid >> 11;          // 0..5
    const int row = (q < 3 ? q : q - 3) * DIM + nb * 16 + (l & 15);
    const float* src = (q < 3 ? p.w_ih : p.w_hh)
                       + (size_t)row * DIM + kt * 32 + (l >> 4) * 8;
    const float4 lo = ((const float4*)src)[0];
    const float4 hi = ((const float4*)src)[1];
    bf16x8 v;
    v[0] = (short)f2bf(lo.x); v[1] = (short)f2bf(lo.y);
    v[2] = (short)f2bf(lo.z); v[3] = (short)f2bf(lo.w);
    v[4] = (short)f2bf(hi.x); v[5] = (short)f2bf(hi.y);
    v[6] = (short)f2bf(hi.z); v[7] = (short)f2bf(hi.w);
    *(bf16x8*)(p.blobBw + (size_t)gid * 8) = v;
  } else {
    // fc1_w -> bf16 linear [row][col]
    const int j = (gid - 12288) * 8;   // 0..32760
    const float4 lo = *(const float4*)(p.fc1_w + j);
    const float4 hi = *(const float4*)(p.fc1_w + j + 4);
    bf16x8 v;
    v[0] = (short)f2bf(lo.x); v[1] = (short)f2bf(lo.y);
    v[2] = (short)f2bf(lo.z); v[3] = (short)f2bf(lo.w);
    v[4] = (short)f2bf(hi.x); v[5] = (short)f2bf(hi.y);
    v[6] = (short)f2bf(hi.z); v[7] = (short)f2bf(hi.w);
    *(bf16x8*)(p.blobFc1 + j) = v;
  }
  if (gid < 4096) {   // h0 fp32 + h0^T bf16
    const int n = gid >> 7, d = gid & 127;
    const float v = p.ne_w[p.nt[n] * DIM + d] + p.te_w[p.tr[n] * DIM + d];
    p.blobH0[gid] = v;
    p.blobHT[d * 32 + n] = f2bf(v);
  }
}

// --------- GRU: every block computes the full problem redundantly -----------
// (keeps all 256 CUs busy with real work -> sustained utilization -> DPM
//  ramps SCLK across graph replays; block 0 writes the output)
struct GnnParams {
  const float* ef_w;
  const float* b_ih; const float* b_hh;
  const float* ln_g; const float* ln_b;
  const float* fc1_b;
  const float* ln2_g; const float* ln2_b;
  const float* fc2_w; const float* fc2_b;
  const int* hA; const int* hF;
  const unsigned short* blobBw; const unsigned short* blobFc1;
  const float* blobH0; const unsigned short* blobHT;
  float* out;
};

__global__ __launch_bounds__(NTHR_G, 2) void gnn_kernel(GnnParams p)
{
  const int t = threadIdx.x;
  const int nb = t >> 6;          // wave 0..7 (= dim-tile)
  const int l = t & 63;
  const int g = l >> 4;           // 0..3
  const int ln16 = l & 15;
  const int dd = nb * 16 + ln16;  // this lane's dim

  __shared__ __align__(16) float sh[N_NODES * SHS];        // fp32 h (head)
  __shared__ __align__(16) float sBnorm[N_NODES * SHS];    // (F@ef_w)/cnt
  __shared__ __align__(16) unsigned short hbf [N_NODES * SBS]; // bf16 h
  __shared__ __align__(16) unsigned short hagg[N_NODES * SBS]; // bf16 agg
  __shared__ __align__(16) unsigned short hbT [DIM * STS];     // bf16 h^T
  __shared__ __align__(16) unsigned short anormP[2 * 64 * 8];  // A-frags A/cnt
  __shared__ __align__(16) float part_s[N_NODES * 8];
  __shared__ __align__(16) float part_q[N_NODES * 8];
  __shared__ __align__(16) int   sAraw[N_NODES * N_NODES];
  __shared__ float sicnt[N_NODES];
  __shared__ int   shFs[192];
  __shared__ float sef[6 * DIM];
  __shared__ float pooled[2 * DIM], svals[DIM], red[4];

  // ======== issue ALL global loads up front (independent) ====================
  bf16x8 Bw[6][4];
#pragma unroll
  for (int q = 0; q < 6; ++q)
#pragma unroll
    for (int kt = 0; kt < 4; ++kt)
      Bw[q][kt] = *(const bf16x8*)(p.blobBw + (size_t)((((q * 8 + nb) * 4 + kt) * 64 + l)) * 8);

  bf16x8 F1[8];
#pragma unroll
  for (int j = 0; j < 8; ++j)
    F1[j] = *(const bf16x8*)(p.blobFc1 + (size_t)t * 64 + j * 8);

  const float bi0 = p.b_ih[dd], bi1 = p.b_ih[DIM + dd], bi2 = p.b_ih[2 * DIM + dd];
  const float bh0 = p.b_hh[dd], bh1 = p.b_hh[DIM + dd], bh2 = p.b_hh[2 * DIM + dd];
  const float gdd = p.ln_g[dd], bdd = p.ln_b[dd];
  float ln2g_ = 0.f, ln2b_ = 0.f, f2w_ = 0.f;
  if (t < DIM) { ln2g_ = p.ln2_g[t]; ln2b_ = p.ln2_b[t]; f2w_ = p.fc2_w[t]; }
  const float fc1b_ = p.fc1_b[t >> 2];
  const float fc2b  = p.fc2_b[0];

  const float4 h0a = *(const float4*)(p.blobH0 + t * 8);
  const float4 h0b = *(const float4*)(p.blobH0 + t * 8 + 4);
  const bf16x8 hTv = *(const bf16x8*)(p.blobHT + t * 8);
  const int2  hAv  = *(const int2*)(p.hA + t * 2);
  int   hFv = 0;   if (t < 192) hFv = p.hF[t];
  float2 efv = {0.f, 0.f}; if (t < 384) efv = *(const float2*)(p.ef_w + t * 2);

  // ======== LDS staging ======================================================
  {
    const int n = (t * 8) >> 7, d0 = (t * 8) & 127;
    *(float4*)&sh[n * SHS + d0]     = h0a;
    *(float4*)&sh[n * SHS + d0 + 4] = h0b;
    bf16x8 hb;
    hb[0] = (short)f2bf(h0a.x); hb[1] = (short)f2bf(h0a.y);
    hb[2] = (short)f2bf(h0a.z); hb[3] = (short)f2bf(h0a.w);
    hb[4] = (short)f2bf(h0b.x); hb[5] = (short)f2bf(h0b.y);
    hb[6] = (short)f2bf(h0b.z); hb[7] = (short)f2bf(h0b.w);
    *(bf16x8*)&hbf[n * SBS + d0] = hb;
  }
  {
    const int d = (t * 8) >> 5, n0 = (t * 8) & 31;
    *(bf16x8*)&hbT[d * STS + n0] = hTv;
  }
  *(int2*)&sAraw[t * 2] = hAv;
  if (t < 192) shFs[t] = hFv;
  if (t < 384) *(float2*)&sef[t * 2] = efv;
  __syncthreads();

  if (t < 32) {
    int c = 0;
#pragma unroll
    for (int s = 0; s < 32; ++s) c += sAraw[t * 32 + s];
    sicnt[t] = 1.0f / fmaxf((float)c, 1.0f);
  }
  __syncthreads();

  for (int i = t; i < N_NODES * DIM; i += NTHR_G) {   // Bnorm
    const int n = i >> 7, d2 = i & 127;
    float acc = 0.f;
#pragma unroll
    for (int f = 0; f < 6; ++f)
      acc = fmaf((float)shFs[n * 6 + f], sef[f * DIM + d2], acc);
    sBnorm[n * SHS + d2] = acc * sicnt[n];
  }
  if (t < 128) {                      // Anorm A-fragments (2 m-tiles)
    const int mt = t >> 6, ll = t & 63;
    const int m = mt * 16 + (ll & 15);
    const float ic = sicnt[m];
#pragma unroll
    for (int j = 0; j < 8; ++j) {
      const int s = (ll >> 4) * 8 + j;
      anormP[(mt * 64 + ll) * 8 + j] = f2bf((float)sAraw[m * 32 + s] * ic);
    }
  }
  __syncthreads();

  // register caches + h in registers
  const bf16x8 aN0 = *(const bf16x8*)&anormP[l * 8];
  const bf16x8 aN1 = *(const bf16x8*)&anormP[(64 + l) * 8];
  f32x4 cB0, cB1;
#pragma unroll
  for (int j = 0; j < 4; ++j) {
    cB0[j] = sBnorm[(g * 4 + j) * SHS + dd];
    cB1[j] = sBnorm[(16 + g * 4 + j) * SHS + dd];
  }
  const f32x4 fz = {0.f, 0.f, 0.f, 0.f};

  float hv00, hv01, hv02, hv03, hv10, hv11, hv12, hv13;
  float hp00, hp01, hp02, hp03, hp10, hp11, hp12, hp13;
  #define FOREACH8(M) M(0,0,hv00,hp00) M(0,1,hv01,hp01) M(0,2,hv02,hp02) M(0,3,hv03,hp03) \
                      M(1,0,hv10,hp10) M(1,1,hv11,hp11) M(1,2,hv12,hp12) M(1,3,hv13,hp13)
  #define HV_INIT(MT,J,HV,HP) HV = sh[(MT*16 + g*4 + J) * SHS + dd];
  FOREACH8(HV_INIT)
  #undef HV_INIT

  // ---------------- 5 GRU iterations ----------------------------------------
  for (int it = 0; it < 5; ++it) {
    // Phase A: agg = Anorm@H + Bnorm
    {
      const bf16x8 bT = *(const bf16x8*)&hbT[dd * STS + g * 8];
      const f32x4 d0 = __builtin_amdgcn_mfma_f32_16x16x32_bf16(aN0, bT, cB0, 0, 0, 0);
      const f32x4 d1 = __builtin_amdgcn_mfma_f32_16x16x32_bf16(aN1, bT, cB1, 0, 0, 0);
#pragma unroll
      for (int j = 0; j < 4; ++j) {
        hagg[(g * 4 + j) * SBS + dd]      = f2bf(d0[j]);
        hagg[(16 + g * 4 + j) * SBS + dd] = f2bf(d1[j]);
      }
    }
    __syncthreads();   // hagg ready; prev-iter hbf writes visible

    // Phase B: C_ih = agg@w_ih^T, C_hh = h@w_hh^T — weights in VGPRs
    f32x4 Ai[2][3], Hh[2][3];
#pragma unroll
    for (int mt = 0; mt < 2; ++mt)
#pragma unroll
      for (int q = 0; q < 3; ++q) { Ai[mt][q] = fz; Hh[mt][q] = fz; }
#pragma unroll
    for (int kt = 0; kt < 4; ++kt) {
      const int ko = kt * 32 + g * 8;
      const bf16x8 ai0 = *(const bf16x8*)&hagg[ln16        * SBS + ko];
      const bf16x8 ai1 = *(const bf16x8*)&hagg[(16 + ln16) * SBS + ko];
      const bf16x8 ah0 = *(const bf16x8*)&hbf [ln16        * SBS + ko];
      const bf16x8 ah1 = *(const bf16x8*)&hbf [(16 + ln16) * SBS + ko];
#pragma unroll
      for (int q = 0; q < 3; ++q) {
        Ai[0][q] = __builtin_amdgcn_mfma_f32_16x16x32_bf16(ai0, Bw[q][kt],     Ai[0][q], 0, 0, 0);
        Ai[1][q] = __builtin_amdgcn_mfma_f32_16x16x32_bf16(ai1, Bw[q][kt],     Ai[1][q], 0, 0, 0);
        Hh[0][q] = __builtin_amdgcn_mfma_f32_16x16x32_bf16(ah0, Bw[3 + q][kt], Hh[0][q], 0, 0, 0);
        Hh[1][q] = __builtin_amdgcn_mfma_f32_16x16x32_bf16(ah1, Bw[3 + q][kt], Hh[1][q], 0, 0, 0);
      }
    }

    // Phase C: gates (D-layout: dim = l&15, node = g*4+j)
    #define GATE(MT,J,HV,HP)                                                   \
    {                                                                          \
      const float r_ = sigm(Ai[MT][0][J] + bi0 + Hh[MT][0][J] + bh0);          \
      const float z_ = sigm(Ai[MT][1][J] + bi1 + Hh[MT][1][J] + bh1);          \
      const float n_ = ftanh(Ai[MT][2][J] + bi2 + r_ * (Hh[MT][2][J] + bh2));  \
      HP = (1.f - z_) * n_ + z_ * HV;                                          \
    }
    FOREACH8(GATE)
    #undef GATE

    // LN partials across the 16 dim-lanes of this wave
    #define RED16(MT,J,HV,HP)                                                  \
    {                                                                          \
      float s_ = HP, q_ = HP * HP;                                             \
      s_ += __shfl_xor(s_, 1, 16);  q_ += __shfl_xor(q_, 1, 16);               \
      s_ += __shfl_xor(s_, 2, 16);  q_ += __shfl_xor(q_, 2, 16);               \
      s_ += __shfl_xor(s_, 4, 16);  q_ += __shfl_xor(q_, 4, 16);               \
      s_ += __shfl_xor(s_, 8, 16);  q_ += __shfl_xor(q_, 8, 16);               \
      if (ln16 == 0) {                                                         \
        const int m_ = MT * 16 + g * 4 + J;                                    \
        part_s[m_ * 8 + nb] = s_;  part_q[m_ * 8 + nb] = q_;                   \
      }                                                                        \
    }
    FOREACH8(RED16)
    #undef RED16
    __syncthreads();   // partials visible

    // per-thread mean/rstd + LN write-back
    #define FIN(MT,J,HV,HP)                                                    \
    {                                                                          \
      const int m_ = MT * 16 + g * 4 + J;                                      \
      const float4 s0 = *(const float4*)&part_s[m_ * 8];                       \
      const float4 s1 = *(const float4*)&part_s[m_ * 8 + 4];                   \
      const float4 q0 = *(const float4*)&part_q[m_ * 8];                       \
      const float4 q1 = *(const float4*)&part_q[m_ * 8 + 4];                   \
      const float mean = (((s0.x + s0.y) + (s0.z + s0.w)) +                    \
                          ((s1.x + s1.y) + (s1.z + s1.w))) * (1.0f / DIM);     \
      const float var  = (((q0.x + q0.y) + (q0.z + q0.w)) +                    \
                          ((q1.x + q1.y) + (q1.z + q1.w))) * (1.0f / DIM)      \
                         - mean * mean;                                        \
      const float rstd = rsqrtf(var + 1e-5f);                                  \
      const float hn_ = (HP - mean) * rstd * gdd + bdd;                        \
      HV = hn_;                                                                \
      const unsigned short bv_ = f2bf(hn_);                                    \
      hbf[m_ * SBS + dd] = bv_;                                                \
      hbT[dd * STS + m_] = bv_;                                                \
      sh[m_ * SHS + dd] = hn_;                                                 \
    }
    FOREACH8(FIN)
    #undef FIN
    // no sync here: next Phase A reads only own-wave hbT rows; cross-wave
    // hbf/hagg consumers are fenced by the Phase-A sync. (Validated R8-R12.)
  }
  __syncthreads();   // sh complete for head
  #undef FOREACH8

  // ---------------- head (zero global loads) ---------------------------------
  if (t < DIM) {
    float s = 0.f, mx = -INFINITY;
#pragma unroll
    for (int n2 = 0; n2 < N_NODES; ++n2) {
      const float v = sh[n2 * SHS + t];
      s += v; mx = fmaxf(mx, v);
    }
    pooled[t]       = s * (1.0f / N_NODES);
    pooled[t + DIM] = mx;
  }
  __syncthreads();

  // fc1 from registers: 4 lanes per output row
  {
    const int part = t & 3;
    float acc = 0.f;
#pragma unroll
    for (int j = 0; j < 8; ++j) {
      const bf16x8 f = F1[j];
#pragma unroll
      for (int e = 0; e < 8; ++e)
        acc = fmaf(bf2f((unsigned short)f[e]), pooled[part * 64 + j * 8 + e], acc);
    }
    acc += __shfl_xor(acc, 1, 4);
    acc += __shfl_xor(acc, 2, 4);
    if (part == 0) svals[t >> 2] = acc + fc1b_;
  }
  __syncthreads();

  if (t < DIM) {
    float s = svals[t];
#pragma unroll
    for (int o = 32; o > 0; o >>= 1) s += __shfl_down(s, o, 64);
    if ((t & 63) == 0) red[t >> 6] = s;
  }
  __syncthreads();
  const float mean2 = (red[0] + red[1]) * (1.0f / DIM);
  if (t < DIM) {
    const float dx = svals[t] - mean2;
    float s = dx * dx;
#pragma unroll
    for (int o = 32; o > 0; o >>= 1) s += __shfl_down(s, o, 64);
    if ((t & 63) == 0) red[2 + (t >> 6)] = s;
  }
  __syncthreads();
  const float var2  = (red[2] + red[3]) * (1.0f / DIM);
  const float rstd2 = rsqrtf(var2 + 1e-5f);
  __syncthreads();
  if (t < DIM) {
    float x = (svals[t] - mean2) * rstd2 * ln2g_ + ln2b_;
    x = fmaxf(x, 0.f);
    float s = x * f2w_;
#pragma unroll
    for (int o = 32; o > 0; o >>= 1) s += __shfl_down(s, o, 64);
    if ((t & 63) == 0) red[t >> 6] = s;
  }
  __syncthreads();
  if (blockIdx.x == 0 && t == 0) p.out[0] = red[0] + red[1] + fc2b;
}

// ---------------------------------------------------------------------------
extern "C" void kernel_launch(void* const* d_in, const int* in_sizes, int n_in,
                              void* d_out, int out_size, void* d_ws, size_t ws_size,
                              hipStream_t stream)
{
  const int*   nt    = (const int*)d_in[0];
  const int*   tr    = (const int*)d_in[1];
  const int*   es    = (const int*)d_in[2];
  const int*   ed    = (const int*)d_in[3];
  const int*   ef    = (const int*)d_in[4];
  const float* ne_w  = (const float*)d_in[5];
  const float* te_w  = (const float*)d_in[6];
  const float* ef_w  = (const float*)d_in[7];
  const float* w_ih  = (const float*)d_in[8];
  const float* w_hh  = (const float*)d_in[9];
  const float* b_ih  = (const float*)d_in[10];
  const float* b_hh  = (const float*)d_in[11];
  const float* ln_g  = (const float*)d_in[12];
  const float* ln_b  = (const float*)d_in[13];
  const float* fc1_w = (const float*)d_in[14];
  const float* fc1_b = (const float*)d_in[15];
  const float* ln2_g = (const float*)d_in[16];
  const float* ln2_b = (const float*)d_in[17];
  const float* fc2_w = (const float*)d_in[18];
  const float* fc2_b = (const float*)d_in[19];

  const int E = in_sizes[2];

  // ws layout:
  // hA[1024]@0 | hF[192]@4096 | blobBw@8192 (192K) | blobFc1@204800 (64K)
  // | blobH0@270336 (16K) | blobHT@286720 (8K)
  int*            hA      = (int*)d_ws;
  int*            hF      = (int*)((char*)d_ws + 4096);
  unsigned short* blobBw  = (unsigned short*)((char*)d_ws + 8192);
  unsigned short* blobFc1 = (unsigned short*)((char*)d_ws + 204800);
  float*          blobH0  = (float*)((char*)d_ws + 270336);
  unsigned short* blobHT  = (unsigned short*)((char*)d_ws + 286720);

  hipMemsetAsync(d_ws, 0, 4864, stream);

  PrepParams pp;
  pp.es = es; pp.ed = ed; pp.ef = ef; pp.E = E;
  pp.w_ih = w_ih; pp.w_hh = w_hh; pp.fc1_w = fc1_w;
  pp.nt = nt; pp.tr = tr; pp.ne_w = ne_w; pp.te_w = te_w;
  pp.hA = hA; pp.hF = hF;
  pp.blobBw = blobBw; pp.blobFc1 = blobFc1;
  pp.blobH0 = blobH0; pp.blobHT = blobHT;
  hipLaunchKernelGGL(prep_kernel, dim3(PREP_BLOCKS), dim3(NTHR_P), 0, stream, pp);

  GnnParams prm;
  prm.ef_w = ef_w;
  prm.b_ih = b_ih; prm.b_hh = b_hh;
  prm.ln_g = ln_g; prm.ln_b = ln_b;
  prm.fc1_b = fc1_b;
  prm.ln2_g = ln2_g; prm.ln2_b = ln2_b;
  prm.fc2_w = fc2_w; prm.fc2_b = fc2_b;
  prm.hA = hA; prm.hF = hF;
  prm.blobBw = blobBw; prm.blobFc1 = blobFc1;
  prm.blobH0 = blobH0; prm.blobHT = blobHT;
  prm.out = (float*)d_out;
  hipLaunchKernelGGL(gnn_kernel, dim3(GNN_BLOCKS), dim3(NTHR_G), 0, stream, prm);
}

// Round 14
// 37.525 us; speedup vs baseline: 1.7763x; 1.7763x over previous
//
#include <hip/hip_runtime.h>
#include <math.h>

#define N_NODES 32
#define DIM     128
#define NTHR_H  256
#define HIST_BLOCKS 64
#define NTHR_P  256
#define PACK_BLOCKS 48
#define NTHR_G  512   // 8 waves, 2 waves/SIMD -> 256 VGPR budget

#define SHS 132   // fp32 row stride (elements)
#define SBS 136   // bf16 row stride (elements; 272 B)
#define STS 40    // bf16 transposed stride (80 B)

typedef __attribute__((ext_vector_type(8))) short bf16x8;
typedef __attribute__((ext_vector_type(4))) float f32x4;

// round-to-nearest-even f32 -> bf16 bits (finite values only)
__device__ __forceinline__ unsigned short f2bf(float f) {
  unsigned int u = __float_as_uint(f);
  u += 0x7fffu + ((u >> 16) & 1u);
  return (unsigned short)(u >> 16);
}

#define LOG2E 1.44269504088896340736f
__device__ __forceinline__ float fexp2(float x) { return __builtin_amdgcn_exp2f(x); }
__device__ __forceinline__ float frcp(float x)  { return __builtin_amdgcn_rcpf(x); }
__device__ __forceinline__ float sigm(float x)  { return frcp(1.f + fexp2(-LOG2E * x)); }
__device__ __forceinline__ float ftanh(float x) { return 1.f - 2.f * frcp(1.f + fexp2((2.f * LOG2E) * x)); }

// ---------------- histogram over edges (index-only, loop-invariant) ---------
__global__ __launch_bounds__(NTHR_H) void hist_kernel(
    const int* __restrict__ es, const int* __restrict__ ed,
    const int* __restrict__ ef, int E,
    int* __restrict__ hA, int* __restrict__ hF)
{
  __shared__ int lA[N_NODES * N_NODES];
  __shared__ int lF[N_NODES * 6];
  const int t = threadIdx.x;
  for (int i = t; i < N_NODES * N_NODES; i += NTHR_H) lA[i] = 0;
  for (int i = t; i < N_NODES * 6;       i += NTHR_H) lF[i] = 0;
  __syncthreads();

  const int E4 = E >> 2;
  const int4* es4 = (const int4*)es;
  const int4* ed4 = (const int4*)ed;
  const int4* ef4 = (const int4*)ef;
  #define DO_EDGE(S, D, F) \
    if ((unsigned)(S) < N_NODES && (unsigned)(D) < N_NODES) { \
      atomicAdd(&lA[(D) * N_NODES + (S)], 1); \
      atomicAdd(&lF[(D) * 6 + (F)], 1); }
  for (int i = blockIdx.x * NTHR_H + t; i < E4; i += gridDim.x * NTHR_H) {
    int4 s4 = es4[i], d4 = ed4[i], f4 = ef4[i];
    DO_EDGE(s4.x, d4.x, f4.x)
    DO_EDGE(s4.y, d4.y, f4.y)
    DO_EDGE(s4.z, d4.z, f4.z)
    DO_EDGE(s4.w, d4.w, f4.w)
  }
  if (blockIdx.x == 0) {
    for (int e = (E4 << 2) + t; e < E; e += NTHR_H) {
      int s = es[e], d = ed[e], f = ef[e];
      DO_EDGE(s, d, f)
    }
  }
  #undef DO_EDGE
  __syncthreads();
  for (int i = t; i < N_NODES * N_NODES; i += NTHR_H) { int v = lA[i]; if (v) atomicAdd(&hA[i], v); }
  for (int i = t; i < N_NODES * 6;       i += NTHR_H) { int v = lF[i]; if (v) atomicAdd(&hF[i], v); }
}

// ------- pack [w_ih;w_hh] into bf16 fragments; zero hA/hF (runs first) ------
// Fragment: lane l holds W[row][k] with row = nt*16 + (l&15),
// k = kt*32 + (l>>4)*8 + j. Same lane map serves as A-frag (D = W @ X^T).
__global__ __launch_bounds__(NTHR_P) void pack_kernel(
    const float* __restrict__ w_ih, const float* __restrict__ w_hh,
    unsigned short* __restrict__ pack,
    int* __restrict__ hA, int* __restrict__ hF)
{
  if (blockIdx.x == 0) {
    for (int i = threadIdx.x; i < N_NODES * N_NODES; i += NTHR_P) hA[i] = 0;
    for (int i = threadIdx.x; i < N_NODES * 6;       i += NTHR_P) hF[i] = 0;
  }
  const int gid = blockIdx.x * NTHR_P + threadIdx.x;  // 0..12287
  const int T = gid >> 6;          // 0..191
  const int l = gid & 63;
  const int mm = T / 96;           // 0 = w_ih, 1 = w_hh
  const int t2 = T % 96;
  const int nt = t2 >> 2;          // 0..23 row-tile over 384
  const int kt = t2 & 3;
  const int row = nt * 16 + (l & 15);
  const int k   = kt * 32 + (l >> 4) * 8;
  const float* src = (mm ? w_hh : w_ih) + (size_t)row * DIM + k;
  bf16x8 out;
#pragma unroll
  for (int j = 0; j < 8; ++j) out[j] = (short)f2bf(src[j]);
  *(bf16x8*)(pack + (size_t)T * 512 + l * 8) = out;
}

// --------- single-workgroup GRU, transposed MFMA orientation ----------------
// Phase A: agg^T = H^T @ Anorm^T + Bnorm^T  (D rows = dims, cols = nodes)
// Phase B: G^T  = W  @ X^T                  (A = packed W frags, unchanged)
// Lane owns 4 consecutive dims x 1 node per (tile, ntile) -> LN needs only
// in-lane 4-sum + 2 shfls + one small LDS partial exchange.
struct GnnParams {
  const int* nt; const int* tr;
  const float* ne_w; const float* te_w; const float* ef_w;
  const float* b_ih; const float* b_hh;
  const float* ln_g; const float* ln_b;
  const float* fc1_w; const float* fc1_b;
  const float* ln2_g; const float* ln2_b;
  const float* fc2_w; const float* fc2_b;
  const int* hA; const int* hF;
  const unsigned short* pack;
  float* out;
};

__global__ __launch_bounds__(NTHR_G, 2) void gnn_kernel(GnnParams p)
{
  const int t  = threadIdx.x;
  const int W  = t >> 6;           // wave 0..7 = dim-tile
  const int l  = t & 63;
  const int g  = l >> 4;           // row-group 0..3
  const int li = l & 15;           // node-within-tile / row-within-tile
  const int d0 = W * 16 + g * 4;   // this lane's 4 dims: d0..d0+3

  __shared__ __align__(16) float sh[N_NODES * SHS];        // fp32 h (head)
  __shared__ __align__(16) float sBnorm[N_NODES * SHS];    // (F@ef_w)/cnt
  __shared__ __align__(16) unsigned short hbf  [N_NODES * SBS]; // bf16 h [node][dim]
  __shared__ __align__(16) unsigned short aggTT[N_NODES * SBS]; // bf16 agg [node][dim]
  __shared__ __align__(16) unsigned short hbT  [DIM * STS];     // bf16 h^T [dim][node]
  __shared__ __align__(16) unsigned short anormP[2 * 64 * 8];   // Anorm frags
  __shared__ __align__(16) float part_s[N_NODES * 8];
  __shared__ __align__(16) float part_q[N_NODES * 8];
  __shared__ float sicnt[N_NODES];
  __shared__ int   snt[N_NODES], str[N_NODES], shF[192];
  __shared__ float pooled[2 * DIM], svals[DIM], red[4];

  // ---- weight fragments -> registers (24 x b128 from packed blob) ----------
  bf16x8 Bw[6][4];
#pragma unroll
  for (int q = 0; q < 6; ++q)
#pragma unroll
    for (int kt = 0; kt < 4; ++kt) {
      const int T = (q < 3) ? ((q * 8 + W) * 4 + kt)
                            : (96 + ((q - 3) * 8 + W) * 4 + kt);
      Bw[q][kt] = *(const bf16x8*)(p.pack + (size_t)T * 512 + (size_t)l * 8);
    }

  // per-lane 4-dim parameter vectors
  const f32x4 bir = *(const f32x4*)&p.b_ih[d0];
  const f32x4 biz = *(const f32x4*)&p.b_ih[DIM + d0];
  const f32x4 bin = *(const f32x4*)&p.b_ih[2 * DIM + d0];
  const f32x4 bhr = *(const f32x4*)&p.b_hh[d0];
  const f32x4 bhz = *(const f32x4*)&p.b_hh[DIM + d0];
  const f32x4 bhn = *(const f32x4*)&p.b_hh[2 * DIM + d0];
  const f32x4 lg4 = *(const f32x4*)&p.ln_g[d0];
  const f32x4 lb4 = *(const f32x4*)&p.ln_b[d0];

  // ---- small tables ----------------------------------------------------------
  if (t < 32) { snt[t] = p.nt[t]; str[t] = p.tr[t]; }
  if (t < 192) shF[t] = p.hF[t];
  if (t < 32) {
    int c = 0;
#pragma unroll
    for (int s = 0; s < 32; ++s) c += p.hA[t * 32 + s];
    sicnt[t] = 1.0f / fmaxf((float)c, 1.0f);
  }
  __syncthreads();

  // h0 (fp32 + bf16 + transposed) and Bnorm
  for (int i = t; i < N_NODES * DIM; i += NTHR_G) {
    const int n = i >> 7, d2 = i & (DIM - 1);
    const float v = p.ne_w[snt[n] * DIM + d2] + p.te_w[str[n] * DIM + d2];
    sh[n * SHS + d2] = v;
    const unsigned short bv = f2bf(v);
    hbf[n * SBS + d2] = bv;
    hbT[d2 * STS + n] = bv;
    float acc = 0.f;
#pragma unroll
    for (int f = 0; f < 6; ++f)
      acc = fmaf((float)shF[n * 6 + f], p.ef_w[f * DIM + d2], acc);
    sBnorm[n * SHS + d2] = acc * sicnt[n];
  }
  if (t < 128) {   // Anorm fragments (used as B-operand; same lane map)
    const int mt = t >> 6, ll = t & 63;
    const int m = mt * 16 + (ll & 15);
    const float ic = sicnt[m];
#pragma unroll
    for (int j = 0; j < 8; ++j) {
      const int s = (ll >> 4) * 8 + j;
      anormP[(mt * 64 + ll) * 8 + j] = f2bf((float)p.hA[m * 32 + s] * ic);
    }
  }
  __syncthreads();

  // loop-invariant register caches
  const bf16x8 aN0 = *(const bf16x8*)&anormP[l * 8];         // ntile 0
  const bf16x8 aN1 = *(const bf16x8*)&anormP[(64 + l) * 8];  // ntile 1
  const f32x4 cB0 = *(const f32x4*)&sBnorm[(li)      * SHS + d0];  // Bnorm^T
  const f32x4 cB1 = *(const f32x4*)&sBnorm[(16 + li) * SHS + d0];
  f32x4 hv0 = *(const f32x4*)&sh[(li)      * SHS + d0];      // h in regs
  f32x4 hv1 = *(const f32x4*)&sh[(16 + li) * SHS + d0];
  const f32x4 fz = {0.f, 0.f, 0.f, 0.f};

  // ---------------- 5 GRU iterations ----------------------------------------
  for (int it = 0; it < 5; ++it) {
    // Phase A: agg^T tile (M=16 dims of wave W, N=2x16 nodes, K=32 src)
    {
      const bf16x8 hT = *(const bf16x8*)&hbT[(W * 16 + li) * STS + g * 8];
      const f32x4 dA0 = __builtin_amdgcn_mfma_f32_16x16x32_bf16(hT, aN0, cB0, 0, 0, 0);
      const f32x4 dA1 = __builtin_amdgcn_mfma_f32_16x16x32_bf16(hT, aN1, cB1, 0, 0, 0);
      unsigned long long w0 =
          (unsigned long long)f2bf(dA0[0]) |
          ((unsigned long long)f2bf(dA0[1]) << 16) |
          ((unsigned long long)f2bf(dA0[2]) << 32) |
          ((unsigned long long)f2bf(dA0[3]) << 48);
      unsigned long long w1 =
          (unsigned long long)f2bf(dA1[0]) |
          ((unsigned long long)f2bf(dA1[1]) << 16) |
          ((unsigned long long)f2bf(dA1[2]) << 32) |
          ((unsigned long long)f2bf(dA1[3]) << 48);
      *(unsigned long long*)&aggTT[(li)      * SBS + d0] = w0;
      *(unsigned long long*)&aggTT[(16 + li) * SBS + d0] = w1;
    }
    __syncthreads();   // aggTT ready; prev FIN's hbf visible to all waves

    // Phase B: G^T = W @ X^T (A = weight frags in regs)
    f32x4 Ai[3][2], Hh[3][2];
#pragma unroll
    for (int q = 0; q < 3; ++q) {
      Ai[q][0] = fz; Ai[q][1] = fz; Hh[q][0] = fz; Hh[q][1] = fz;
    }
#pragma unroll
    for (int kt = 0; kt < 4; ++kt) {
      const int ko = kt * 32 + g * 8;
      const bf16x8 xA0 = *(const bf16x8*)&aggTT[(li)      * SBS + ko];
      const bf16x8 xA1 = *(const bf16x8*)&aggTT[(16 + li) * SBS + ko];
      const bf16x8 xH0 = *(const bf16x8*)&hbf  [(li)      * SBS + ko];
      const bf16x8 xH1 = *(const bf16x8*)&hbf  [(16 + li) * SBS + ko];
#pragma unroll
      for (int q = 0; q < 3; ++q) {
        Ai[q][0] = __builtin_amdgcn_mfma_f32_16x16x32_bf16(Bw[q][kt],     xA0, Ai[q][0], 0, 0, 0);
        Ai[q][1] = __builtin_amdgcn_mfma_f32_16x16x32_bf16(Bw[q][kt],     xA1, Ai[q][1], 0, 0, 0);
        Hh[q][0] = __builtin_amdgcn_mfma_f32_16x16x32_bf16(Bw[3 + q][kt], xH0, Hh[q][0], 0, 0, 0);
        Hh[q][1] = __builtin_amdgcn_mfma_f32_16x16x32_bf16(Bw[3 + q][kt], xH1, Hh[q][1], 0, 0, 0);
      }
    }

    // gates (4 dims x 2 nodes per lane) + LN partials (2 shfls per quantity)
    f32x4 hp0, hp1;
#pragma unroll
    for (int j = 0; j < 4; ++j) {
      {
        const float r_ = sigm(Ai[0][0][j] + bir[j] + Hh[0][0][j] + bhr[j]);
        const float z_ = sigm(Ai[1][0][j] + biz[j] + Hh[1][0][j] + bhz[j]);
        const float n_ = ftanh(Ai[2][0][j] + bin[j] + r_ * (Hh[2][0][j] + bhn[j]));
        hp0[j] = (1.f - z_) * n_ + z_ * hv0[j];
      }
      {
        const float r_ = sigm(Ai[0][1][j] + bir[j] + Hh[0][1][j] + bhr[j]);
        const float z_ = sigm(Ai[1][1][j] + biz[j] + Hh[1][1][j] + bhz[j]);
        const float n_ = ftanh(Ai[2][1][j] + bin[j] + r_ * (Hh[2][1][j] + bhn[j]));
        hp1[j] = (1.f - z_) * n_ + z_ * hv1[j];
      }
    }
    {
      float s0 = (hp0[0] + hp0[1]) + (hp0[2] + hp0[3]);
      float q0 = (hp0[0] * hp0[0] + hp0[1] * hp0[1]) + (hp0[2] * hp0[2] + hp0[3] * hp0[3]);
      float s1 = (hp1[0] + hp1[1]) + (hp1[2] + hp1[3]);
      float q1 = (hp1[0] * hp1[0] + hp1[1] * hp1[1]) + (hp1[2] * hp1[2] + hp1[3] * hp1[3]);
      s0 += __shfl_xor(s0, 16); q0 += __shfl_xor(q0, 16);
      s1 += __shfl_xor(s1, 16); q1 += __shfl_xor(q1, 16);
      s0 += __shfl_xor(s0, 32); q0 += __shfl_xor(q0, 32);
      s1 += __shfl_xor(s1, 32); q1 += __shfl_xor(q1, 32);
      if (g == 0) {
        part_s[(li)      * 8 + W] = s0;  part_q[(li)      * 8 + W] = q0;
        part_s[(16 + li) * 8 + W] = s1;  part_q[(16 + li) * 8 + W] = q1;
      }
    }
    __syncthreads();   // partials visible

    // FIN: mean/rstd per node (8 b128 reads) + LN write-back (vector writes)
    #define FIN_NODE(NODE, HP, HV)                                             \
    {                                                                          \
      const f32x4 s0 = *(const f32x4*)&part_s[(NODE) * 8];                     \
      const f32x4 s1 = *(const f32x4*)&part_s[(NODE) * 8 + 4];                 \
      const f32x4 q0 = *(const f32x4*)&part_q[(NODE) * 8];                     \
      const f32x4 q1 = *(const f32x4*)&part_q[(NODE) * 8 + 4];                 \
      const float mean = (((s0[0] + s0[1]) + (s0[2] + s0[3])) +                \
                          ((s1[0] + s1[1]) + (s1[2] + s1[3]))) * (1.0f / DIM); \
      const float var  = (((q0[0] + q0[1]) + (q0[2] + q0[3])) +                \
                          ((q1[0] + q1[1]) + (q1[2] + q1[3]))) * (1.0f / DIM)  \
                         - mean * mean;                                        \
      const float rstd = rsqrtf(var + 1e-5f);                                  \
      _Pragma("unroll")                                                        \
      for (int j = 0; j < 4; ++j)                                              \
        HV[j] = (HP[j] - mean) * rstd * lg4[j] + lb4[j];                       \
      unsigned long long wb =                                                  \
          (unsigned long long)f2bf(HV[0]) |                                    \
          ((unsigned long long)f2bf(HV[1]) << 16) |                            \
          ((unsigned long long)f2bf(HV[2]) << 32) |                            \
          ((unsigned long long)f2bf(HV[3]) << 48);                             \
      *(unsigned long long*)&hbf[(NODE) * SBS + d0] = wb;                      \
      hbT[(d0 + 0) * STS + (NODE)] = (unsigned short)(wb & 0xffff);            \
      hbT[(d0 + 1) * STS + (NODE)] = (unsigned short)((wb >> 16) & 0xffff);    \
      hbT[(d0 + 2) * STS + (NODE)] = (unsigned short)((wb >> 32) & 0xffff);    \
      hbT[(d0 + 3) * STS + (NODE)] = (unsigned short)(wb >> 48);               \
      *(f32x4*)&sh[(NODE) * SHS + d0] = HV;                                    \
    }
    FIN_NODE(li,      hp0, hv0)
    FIN_NODE(16 + li, hp1, hv1)
    #undef FIN_NODE
    // no barrier: next Phase A reads hbT rows of OWN wave's dim-tile only
    // (written just above by this wave); cross-wave hbf/aggTT consumers are
    // fenced by the Phase-A barrier.
  }
  __syncthreads();   // sh complete for head

  // ---------------- head -----------------------------------------------------
  if (t < DIM) {
    float s = 0.f, mx = -INFINITY;
#pragma unroll
    for (int n2 = 0; n2 < N_NODES; ++n2) {
      const float v = sh[n2 * SHS + t];
      s += v; mx = fmaxf(mx, v);
    }
    pooled[t]       = s * (1.0f / N_NODES);
    pooled[t + DIM] = mx;
  }
  __syncthreads();

  // fc1: 4 threads per output row (global fp32 weights, latency-overlapped)
  {
    const int row = t >> 2, part = t & 3;
    const float4* w4f = (const float4*)(p.fc1_w + (size_t)row * 2 * DIM + part * 64);
    const float4* p4  = (const float4*)(pooled + part * 64);
    float acc = 0.f;
#pragma unroll
    for (int k = 0; k < 16; ++k) {
      const float4 wv = w4f[k]; const float4 pv = p4[k];
      acc = fmaf(wv.x, pv.x, acc);
      acc = fmaf(wv.y, pv.y, acc);
      acc = fmaf(wv.z, pv.z, acc);
      acc = fmaf(wv.w, pv.w, acc);
    }
    acc += __shfl_xor(acc, 1);
    acc += __shfl_xor(acc, 2);
    if (part == 0) svals[row] = acc + p.fc1_b[row];
  }
  __syncthreads();

  if (t < DIM) {
    float s = svals[t];
#pragma unroll
    for (int o = 32; o > 0; o >>= 1) s += __shfl_down(s, o, 64);
    if ((t & 63) == 0) red[t >> 6] = s;
  }
  __syncthreads();
  const float mean2 = (red[0] + red[1]) * (1.0f / DIM);
  if (t < DIM) {
    const float dx = svals[t] - mean2;
    float s = dx * dx;
#pragma unroll
    for (int o = 32; o > 0; o >>= 1) s += __shfl_down(s, o, 64);
    if ((t & 63) == 0) red[2 + (t >> 6)] = s;
  }
  __syncthreads();
  const float var2  = (red[2] + red[3]) * (1.0f / DIM);
  const float rstd2 = rsqrtf(var2 + 1e-5f);
  __syncthreads();
  if (t < DIM) {
    float x = (svals[t] - mean2) * rstd2 * p.ln2_g[t] + p.ln2_b[t];
    x = fmaxf(x, 0.f);
    float s = x * p.fc2_w[t];
#pragma unroll
    for (int o = 32; o > 0; o >>= 1) s += __shfl_down(s, o, 64);
    if ((t & 63) == 0) red[t >> 6] = s;
  }
  __syncthreads();
  if (t == 0) p.out[0] = red[0] + red[1] + p.fc2_b[0];
}

// ---------------------------------------------------------------------------
extern "C" void kernel_launch(void* const* d_in, const int* in_sizes, int n_in,
                              void* d_out, int out_size, void* d_ws, size_t ws_size,
                              hipStream_t stream)
{
  const int*   nt    = (const int*)d_in[0];
  const int*   tr    = (const int*)d_in[1];
  const int*   es    = (const int*)d_in[2];
  const int*   ed    = (const int*)d_in[3];
  const int*   ef    = (const int*)d_in[4];
  const float* ne_w  = (const float*)d_in[5];
  const float* te_w  = (const float*)d_in[6];
  const float* ef_w  = (const float*)d_in[7];
  const float* w_ih  = (const float*)d_in[8];
  const float* w_hh  = (const float*)d_in[9];
  const float* b_ih  = (const float*)d_in[10];
  const float* b_hh  = (const float*)d_in[11];
  const float* ln_g  = (const float*)d_in[12];
  const float* ln_b  = (const float*)d_in[13];
  const float* fc1_w = (const float*)d_in[14];
  const float* fc1_b = (const float*)d_in[15];
  const float* ln2_g = (const float*)d_in[16];
  const float* ln2_b = (const float*)d_in[17];
  const float* fc2_w = (const float*)d_in[18];
  const float* fc2_b = (const float*)d_in[19];

  const int E = in_sizes[2];

  // ws: hA[1024]@0 | hF[192]@4096 | blobBw@8192 (192K)
  int*            hA   = (int*)d_ws;
  int*            hF   = (int*)((char*)d_ws + 4096);
  unsigned short* pack = (unsigned short*)((char*)d_ws + 8192);

  // pack zeroes hA/hF (stream order: pack -> hist -> gnn)
  hipLaunchKernelGGL(pack_kernel, dim3(PACK_BLOCKS), dim3(NTHR_P), 0, stream,
                     w_ih, w_hh, pack, hA, hF);
  hipLaunchKernelGGL(hist_kernel, dim3(HIST_BLOCKS), dim3(NTHR_H), 0, stream,
                     es, ed, ef, E, hA, hF);

  GnnParams prm;
  prm.nt = nt; prm.tr = tr;
  prm.ne_w = ne_w; prm.te_w = te_w; prm.ef_w = ef_w;
  prm.b_ih = b_ih; prm.b_hh = b_hh;
  prm.ln_g = ln_g; prm.ln_b = ln_b;
  prm.fc1_w = fc1_w; prm.fc1_b = fc1_b;
  prm.ln2_g = ln2_g; prm.ln2_b = ln2_b;
  prm.fc2_w = fc2_w; prm.fc2_b = fc2_b;
  prm.hA = hA; prm.hF = hF; prm.pack = pack;
  prm.out = (float*)d_out;

  hipLaunchKernelGGL(gnn_kernel, dim3(1), dim3(NTHR_G), 0, stream, prm);
}